// Round 3
// baseline (236.891 us; speedup 1.0000x reference)
//
#include <hip/hip_runtime.h>

#define POOL 7
#define IMG_W 256
#define IMG_C 512
#define NUM_ROIS 1024

typedef float f4 __attribute__((ext_vector_type(4)));

// One block per (roi, py). 128 threads x float4 = 512 channels.
// All 28 loads (7 px x 4 corners) are issued back-to-back before any use:
// addresses are wave-uniform (SGPR), data costs 112 VGPRs -> fits the
// 128-VGPR budget of __launch_bounds__(128,4) at 4 waves/SIMD.
__global__ __launch_bounds__(128, 4) void roi_pool_kernel(
    const float* __restrict__ img,
    const int*   __restrict__ rois,
    float*       __restrict__ out)
{
    const int bid  = blockIdx.x;          // 0..7167
    const int xcd  = bid & 7;
    const int slot = bid >> 3;            // 0..895
    const int rloc = slot / POOL;         // 0..127
    const int py   = slot - rloc * POOL;  // 0..6
    const int roi  = xcd * (NUM_ROIS / 8) + rloc;

    const int4 rb = ((const int4*)rois)[roi];
    const int x1 = __builtin_amdgcn_readfirstlane(rb.x);
    const int y1 = __builtin_amdgcn_readfirstlane(rb.y);
    const int x2 = __builtin_amdgcn_readfirstlane(rb.z);
    const int y2 = __builtin_amdgcn_readfirstlane(rb.w);

    const float h = (float)(y2 - y1);
    const float w = (float)(x2 - x1);
    const float sy = h / (float)POOL;     // reference numerics: h/P, then py*(h/P)
    const float sx = w / (float)POOL;

    const float ys = (float)py * sy;
    const int   y0 = (int)floorf(ys);
    const int   y1i = min(y0 + 1, max(y2 - y1 - 1, 0));
    const float wy = ys - (float)y0;

    const size_t rowstride = (size_t)IMG_W * IMG_C;
    const float* row0 = img + (size_t)(y1 + y0)  * rowstride;
    const float* row1 = img + (size_t)(y1 + y1i) * rowstride;

    const int t = threadIdx.x;            // 0..127
    const int cmax = max(x2 - x1 - 1, 0);

    // --- stage 1: wave-uniform address setup for all 7 px ---
    int   c0a[POOL], c1a[POOL];
    float wxa[POOL];
#pragma unroll
    for (int px = 0; px < POOL; ++px) {
        const float xs = (float)px * sx;
        const int   x0 = (int)floorf(xs);
        const int   x1i = min(x0 + 1, cmax);
        wxa[px] = xs - (float)x0;
        c0a[px] = x1 + x0;
        c1a[px] = x1 + x1i;
    }

    // --- stage 2: issue all 28 independent loads (pure MLP) ---
    f4 v00[POOL], v01[POOL], v10[POOL], v11[POOL];
#pragma unroll
    for (int px = 0; px < POOL; ++px) {
        v00[px] = ((const f4*)(row0 + (size_t)c0a[px] * IMG_C))[t];
        v01[px] = ((const f4*)(row0 + (size_t)c1a[px] * IMG_C))[t];
        v10[px] = ((const f4*)(row1 + (size_t)c0a[px] * IMG_C))[t];
        v11[px] = ((const f4*)(row1 + (size_t)c1a[px] * IMG_C))[t];
    }

    // --- stage 3: blend + store ---
    f4* obase = (f4*)out + ((size_t)roi * (POOL * POOL) + (size_t)py * POOL) * (IMG_C / 4) + t;
#pragma unroll
    for (int px = 0; px < POOL; ++px) {
        const float wx = wxa[px];
        const float w00 = (1.0f - wy) * (1.0f - wx);
        const float w01 = (1.0f - wy) * wx;
        const float w10 = wy * (1.0f - wx);
        const float w11 = wy * wx;
        f4 o = v00[px] * w00 + v01[px] * w01 + v10[px] * w10 + v11[px] * w11;
        __builtin_nontemporal_store(o, obase + px * (IMG_C / 4));
    }
}

extern "C" void kernel_launch(void* const* d_in, const int* in_sizes, int n_in,
                              void* d_out, int out_size, void* d_ws, size_t ws_size,
                              hipStream_t stream) {
    const float* img  = (const float*)d_in[0];
    const int*   rois = (const int*)d_in[1];
    float* out = (float*)d_out;

    dim3 grid(NUM_ROIS * POOL);   // 7168 blocks = (roi, py)
    dim3 block(128);
    roi_pool_kernel<<<grid, block, 0, stream>>>(img, rois, out);
}

// Round 4
// 234.929 us; speedup vs baseline: 1.0083x; 1.0083x over previous
//
#include <hip/hip_runtime.h>

#define POOL 7
#define IMG_W 256
#define IMG_C 512
#define NUM_ROIS 1024

typedef float f4 __attribute__((ext_vector_type(4)));

// ---------------- kernel 1: spatial counting-sort of ROI indices ----------
// Key = 32x32-px tile of (x1,y1), row-major: 8x8 = 64 buckets (x1,y1 < 192
// so only 6x6 occupied, but 64 is cheap). One block, 1024 threads.
// Within-bucket order is nondeterministic (LDS atomics) — harmless: the
// main kernel writes out[roi] for each roi exactly once, any order.
__global__ __launch_bounds__(1024) void sort_rois_kernel(
    const int* __restrict__ rois, int* __restrict__ order)
{
    __shared__ int hist[64];
    __shared__ int base[64];
    const int tid = threadIdx.x;

    if (tid < 64) hist[tid] = 0;
    __syncthreads();

    const int x1 = rois[4 * tid + 0];
    const int y1 = rois[4 * tid + 1];
    const int key = ((y1 >> 5) << 3) | (x1 >> 5);
    const int rank = atomicAdd(&hist[key], 1);
    __syncthreads();

    if (tid == 0) {
        int run = 0;
#pragma unroll
        for (int k = 0; k < 64; ++k) { base[k] = run; run += hist[k]; }
    }
    __syncthreads();

    order[base[key] + rank] = tid;
}

// ---------------- kernel 2: ROI pooling over the sorted order -------------
// Block = (sorted-roi, py). XCD i (bid&7) owns sorted chunk [i*128, (i+1)*128):
// consecutive blocks on one XCD touch spatially adjacent ROIs, so the 4MB
// per-XCD L2 holds the sliding reuse window instead of thrashing.
__global__ __launch_bounds__(128) void roi_pool_kernel(
    const float* __restrict__ img,
    const int*   __restrict__ rois,
    const int*   __restrict__ order,
    float*       __restrict__ out)
{
    const int bid  = blockIdx.x;           // 0..7167
    const int xcd  = bid & 7;
    const int slot = bid >> 3;             // 0..895
    const int sloc = slot / POOL;          // 0..127: position within chunk
    const int py   = slot - sloc * POOL;   // 0..6
    const int sidx = xcd * (NUM_ROIS / 8) + sloc;   // sorted position
    const int roi  = order[sidx];

    const int4 rb = ((const int4*)rois)[roi];
    const int x1 = __builtin_amdgcn_readfirstlane(rb.x);
    const int y1 = __builtin_amdgcn_readfirstlane(rb.y);
    const int x2 = __builtin_amdgcn_readfirstlane(rb.z);
    const int y2 = __builtin_amdgcn_readfirstlane(rb.w);

    const float h = (float)(y2 - y1);
    const float w = (float)(x2 - x1);
    const float sy = h / (float)POOL;      // reference numerics: h/P, then py*(h/P)
    const float sx = w / (float)POOL;

    const float ys = (float)py * sy;
    const int   y0 = (int)floorf(ys);
    const int   y1i = min(y0 + 1, max(y2 - y1 - 1, 0));
    const float wy = ys - (float)y0;

    const size_t rowstride = (size_t)IMG_W * IMG_C;
    const float* row0 = img + (size_t)(y1 + y0)  * rowstride;
    const float* row1 = img + (size_t)(y1 + y1i) * rowstride;

    const int t = threadIdx.x;             // 0..127
    const int cmax = max(x2 - x1 - 1, 0);

    f4* obase = (f4*)out + ((size_t)roi * (POOL * POOL) + (size_t)py * POOL) * (IMG_C / 4) + t;

#pragma unroll
    for (int px = 0; px < POOL; ++px) {
        const float xs = (float)px * sx;
        const int   x0 = (int)floorf(xs);
        const int   x1i = min(x0 + 1, cmax);
        const float wx = xs - (float)x0;
        const int c0 = x1 + x0, c1 = x1 + x1i;

        const f4 v00 = ((const f4*)(row0 + (size_t)c0 * IMG_C))[t];
        const f4 v01 = ((const f4*)(row0 + (size_t)c1 * IMG_C))[t];
        const f4 v10 = ((const f4*)(row1 + (size_t)c0 * IMG_C))[t];
        const f4 v11 = ((const f4*)(row1 + (size_t)c1 * IMG_C))[t];

        const float w00 = (1.0f - wy) * (1.0f - wx);
        const float w01 = (1.0f - wy) * wx;
        const float w10 = wy * (1.0f - wx);
        const float w11 = wy * wx;

        f4 o = v00 * w00 + v01 * w01 + v10 * w10 + v11 * w11;
        __builtin_nontemporal_store(o, obase + px * (IMG_C / 4));
    }
}

extern "C" void kernel_launch(void* const* d_in, const int* in_sizes, int n_in,
                              void* d_out, int out_size, void* d_ws, size_t ws_size,
                              hipStream_t stream) {
    const float* img  = (const float*)d_in[0];
    const int*   rois = (const int*)d_in[1];
    float* out = (float*)d_out;
    int* order = (int*)d_ws;               // 1024 ints, rewritten every call

    sort_rois_kernel<<<1, 1024, 0, stream>>>(rois, order);
    roi_pool_kernel<<<NUM_ROIS * POOL, 128, 0, stream>>>(img, rois, order, out);
}